// Round 9
// baseline (458.638 us; speedup 1.0000x reference)
//
#include <hip/hip_runtime.h>

#define D_MODEL 4544
#define E_QKV   4672     // D + 2*64
#define E_STR   4736     // fused row stride (37*128)
#define E_PAD2  4864     // QKV weight rows padded (19*256)
#define D_PAD   4608     // dense weight rows padded (18*256)
#define NH      71
#define SEQ     1024
#define NB      2
#define M_ROWS  2048     // NB*SEQ

typedef __bf16 bf16_t;
typedef bf16_t bf16x8 __attribute__((ext_vector_type(8)));
typedef float f32x4 __attribute__((ext_vector_type(4)));
typedef float f32x16 __attribute__((ext_vector_type(16)));
typedef unsigned u32x4 __attribute__((ext_vector_type(4)));

typedef __attribute__((address_space(1))) const void* gas_ptr;
typedef __attribute__((address_space(3))) void* las_ptr;

static __device__ __forceinline__ unsigned short f2bf(float f) {
  union { float f; unsigned u; } v; v.f = f;
  unsigned r = (v.u + 0x7fffu + ((v.u >> 16) & 1u)) >> 16;
  return (unsigned short)r;
}

static __device__ __forceinline__ unsigned cvtpk_bf16(float lo, float hi) {
  unsigned r;
  asm("v_cvt_pk_bf16_f32 %0, %1, %2" : "=v"(r) : "v"(lo), "v"(hi));
  return r;
}

static __device__ __forceinline__ float fast_exp2(float x) {
  float r;
  asm("v_exp_f32 %0, %1" : "=v"(r) : "v"(x));
  return r;
}

// dst[rows_pad][cols] bf16 <- src[rows_src][cols] f32, pad rows zeroed.
__global__ void convert_pad(const float* __restrict__ src, unsigned short* __restrict__ dst,
                            int rows_src, int rows_pad, int cols) {
  int idx = blockIdx.x * 256 + threadIdx.x;
  int cols4 = cols >> 2;
  int total = rows_pad * cols4;
  if (idx >= total) return;
  int row = idx / cols4;
  int c4 = (idx - row * cols4) << 2;
  ushort4 o;
  if (row < rows_src) {
    const float4 v = *(const float4*)(src + (size_t)row * cols + c4);
    o.x = f2bf(v.x); o.y = f2bf(v.y); o.z = f2bf(v.z); o.w = f2bf(v.w);
  } else {
    o.x = 0; o.y = 0; o.z = 0; o.w = 0;
  }
  *(ushort4*)(dst + (size_t)row * cols + c4) = o;
}

// ---- 256x256 GEMM: 4-phase/K-tile, cross-phase register lookahead ----
// LDS fragment-ordered (conflict-free). Reads for phase p+1 are issued BEFORE
// phase p's MFMA block into a disjoint reg set -> LDS drain overlaps matrix
// crunch. lgkmcnt(0) before issuing R(p+1) waits exactly R(p) (nothing else
// outstanding). vmcnt(4) per phase gates staged regions (full ledger in notes).
#define REGION(b_, op_, kh_) (((((b_)*2+(op_))*2)+(kh_)) << 13)

#define STAGE(b_, op_, kh_, kt_) do {                                          \
  const unsigned short* _p0 = (op_) ? pB0 : pA0;                               \
  const unsigned short* _p1 = (op_) ? pB1 : pA1;                               \
  const int _koff = ((kt_) << 6) + ((kh_) << 5);                               \
  __builtin_amdgcn_global_load_lds((gas_ptr)(_p0 + _koff),                     \
      (las_ptr)(lds + REGION(b_, op_, kh_) + (wave << 9)), 16, 0, 0);          \
  __builtin_amdgcn_global_load_lds((gas_ptr)(_p1 + _koff),                     \
      (las_ptr)(lds + REGION(b_, op_, kh_) + ((8 + wave) << 9)), 16, 0, 0);    \
} while (0)

#define LDA4G(dst_, b_, kh_, mh_) do {                                         \
  const unsigned short* _ab = lds + REGION(b_, 0, kh_);                        \
  _Pragma("unroll")                                                            \
  for (int _mm = 0; _mm < 4; ++_mm)                                            \
    dst_[_mm] = *(const bf16x8*)&_ab[((wm * 8 + (mh_) * 4 + _mm) << 9) + lane * 8]; \
} while (0)

#define LDB4G(dst_, b_, kh_) do {                                              \
  const unsigned short* _bp = lds + REGION(b_, 1, kh_);                        \
  _Pragma("unroll")                                                            \
  for (int _n = 0; _n < 4; ++_n)                                               \
    dst_[_n] = *(const bf16x8*)&_bp[((wn * 4 + _n) << 9) + lane * 8];          \
} while (0)

#define MFMA16G(af_, bf_, mh_) do {                                            \
  _Pragma("unroll")                                                            \
  for (int _mm = 0; _mm < 4; ++_mm)                                            \
    _Pragma("unroll")                                                          \
    for (int _n = 0; _n < 4; ++_n)                                             \
      acc[(mh_) * 4 + _mm][_n] = __builtin_amdgcn_mfma_f32_16x16x32_bf16(      \
          af_[_mm], bf_[_n], acc[(mh_) * 4 + _mm][_n], 0, 0, 0);               \
} while (0)

// phase prologue: gate, barrier, wait my R(p) done
#define PHASE_SYNC() do {                                                      \
  asm volatile("s_waitcnt vmcnt(4)" ::: "memory");                             \
  __builtin_amdgcn_s_barrier();                                                \
  asm volatile("s_waitcnt lgkmcnt(0)" ::: "memory");                           \
  __builtin_amdgcn_sched_barrier(0);                                           \
} while (0)

__global__ __launch_bounds__(512, 2) void gemm256(
    const unsigned short* __restrict__ A,
    const unsigned short* __restrict__ B,
    float* __restrict__ C,
    int K, int Ntiles, int ldc, int Nact) {
  __shared__ __align__(16) unsigned short lds[65536];   // 128 KiB
  const int tid = threadIdx.x;
  const int wave = tid >> 6, lane = tid & 63;
  const int g = lane >> 4, c = lane & 15;
  const int wm = wave >> 2, wn = wave & 3;
  const int nwg = gridDim.x;
  const int swz = (blockIdx.x & 7) * (nwg >> 3) + (blockIdx.x >> 3);
  const int bm = swz / Ntiles, bn = swz - bm * Ntiles;
  const size_t bRow = (size_t)bm * 256, bCol = (size_t)bn * 256;
  const int NT = K >> 6;

  const unsigned short* pA0 = A + (bRow + (size_t)(wave * 16 + c)) * K + g * 8;
  const unsigned short* pA1 = A + (bRow + (size_t)((8 + wave) * 16 + c)) * K + g * 8;
  const unsigned short* pB0 = B + (bCol + (size_t)(wave * 16 + c)) * K + g * 8;
  const unsigned short* pB1 = B + (bCol + (size_t)((8 + wave) * 16 + c)) * K + g * 8;

  f32x4 acc[8][4] = {};
  bf16x8 aL0[4], aH0[4], bv0[4], aL1[4], aH1[4], bv1[4];

  // prologue: tile0 all 4 regions + tile1 {B-k0, A-k0}  (12 loads)
  STAGE(0, 0, 0, 0); STAGE(0, 1, 0, 0); STAGE(0, 0, 1, 0); STAGE(0, 1, 1, 0);
  STAGE(1, 1, 0, 1); STAGE(1, 0, 0, 1);
  asm volatile("s_waitcnt vmcnt(4)" ::: "memory");   // tile0 landed
  __builtin_amdgcn_s_barrier();
  // R(0): aL0 + bv0 from (buf0, kh0)
  LDA4G(aL0, 0, 0, 0); LDB4G(bv0, 0, 0);
  __builtin_amdgcn_sched_barrier(0);

  for (int t = 0; t < NT; ++t) {
    const int b = t & 1;
    const int tn1 = (t + 1 < NT) ? t + 1 : 0;
    const int tn2 = (t + 2 < NT) ? t + 2 : 0;
    // ---- ph0: issue aH0; stage (b^1,B,k1,t+1); MFMA(aL0,bv0 -> mh0)
    PHASE_SYNC();
    LDA4G(aH0, b, 0, 1);
    STAGE(b ^ 1, 1, 1, tn1);
    __builtin_amdgcn_sched_barrier(0);
    __builtin_amdgcn_s_setprio(1);
    MFMA16G(aL0, bv0, 0);
    __builtin_amdgcn_s_setprio(0);
    // ---- ph1: issue aL1+bv1 (kh1); stage (b^1,A,k1,t+1)+(b,B,k0,t+2); MFMA(aH0,bv0 -> mh1)
    PHASE_SYNC();
    LDA4G(aL1, b, 1, 0); LDB4G(bv1, b, 1);
    STAGE(b ^ 1, 0, 1, tn1); STAGE(b, 1, 0, tn2);
    __builtin_amdgcn_sched_barrier(0);
    __builtin_amdgcn_s_setprio(1);
    MFMA16G(aH0, bv0, 1);
    __builtin_amdgcn_s_setprio(0);
    // ---- ph2: issue aH1; stage (b,A,k0,t+2); MFMA(aL1,bv1 -> mh0)
    PHASE_SYNC();
    LDA4G(aH1, b, 1, 1);
    STAGE(b, 0, 0, tn2);
    __builtin_amdgcn_sched_barrier(0);
    __builtin_amdgcn_s_setprio(1);
    MFMA16G(aL1, bv1, 0);
    __builtin_amdgcn_s_setprio(0);
    // ---- ph3: issue next tile's aL0+bv0 (b^1, kh0); MFMA(aH1,bv1 -> mh1)
    PHASE_SYNC();
    LDA4G(aL0, b ^ 1, 0, 0); LDB4G(bv0, b ^ 1, 0);
    __builtin_amdgcn_sched_barrier(0);
    __builtin_amdgcn_s_setprio(1);
    MFMA16G(aH1, bv1, 1);
    __builtin_amdgcn_s_setprio(0);
  }
  asm volatile("s_waitcnt vmcnt(0) lgkmcnt(0)" ::: "memory");

#pragma unroll
  for (int mm = 0; mm < 8; ++mm) {
#pragma unroll
    for (int n = 0; n < 4; ++n) {
      int col = (int)bCol + wn * 64 + n * 16 + c;
      if (col < Nact) {
#pragma unroll
        for (int r = 0; r < 4; ++r) {
          size_t row = bRow + wm * 128 + mm * 16 + g * 4 + r;
          C[row * ldc + col] = acc[mm][n][r];
        }
      }
    }
  }
}

// fused[n][l][E_STR] f32 -> Qb (RoPE, *0.125*log2e), Kb (RoPE), VTb (V^T)
__global__ void rope_extract(const float* __restrict__ fused,
                             unsigned short* __restrict__ Qb,
                             unsigned short* __restrict__ Kb,
                             unsigned short* __restrict__ VTb) {
  int idx = blockIdx.x * 256 + threadIdx.x;
  const int total = NB * SEQ * 73 * 64;
  if (idx >= total) return;
  int d = idx & 63;
  int t = idx >> 6;
  int h = t % 73;  t /= 73;
  int l = t & (SEQ - 1);
  int n = t >> 10;
  const float* frow = fused + ((size_t)(n * SEQ + l)) * E_STR + h * 64;
  float x = frow[d];
  if (h == 72) {
    VTb[((size_t)(n * 64 + d)) * SEQ + l] = f2bf(x);
    return;
  }
  int dh = d & 31;
  float inv = __expf(-(float)dh * (9.210340371976184f / 32.0f));
  float ang = (float)l * inv;
  float sn, cs;
  __sincosf(ang, &sn, &cs);
  float xr = frow[(d < 32) ? d + 32 : d - 32];
  float rh = (d < 32) ? -xr : xr;
  float out = x * cs + rh * sn;
  if (h == 71) {
    Kb[((size_t)(n * SEQ + l)) * 64 + d] = f2bf(out);
  } else {
    Qb[(((size_t)(n * NH + h)) * SEQ + l) * 64 + d] = f2bf(out * 0.1803368801111204f);
  }
}

// Swapped-QK^T flash MQA with per-wave causal pairing (unchanged).
__global__ __launch_bounds__(128) void attn_kernel(
    const unsigned short* __restrict__ Qb,
    const unsigned short* __restrict__ Kb,
    const unsigned short* __restrict__ VTb,
    unsigned short* __restrict__ attnb) {
  const int h = blockIdx.y, n = blockIdx.z;
  const int wave = threadIdx.x >> 6, lane = threadIdx.x & 63;
  const int c = lane & 31, hi = lane >> 5;
  const int gw = blockIdx.x * 2 + wave;   // 0..15

  const unsigned short* kbase = Kb + (size_t)n * SEQ * 64;
  const unsigned short* vtbase = VTb + (size_t)n * 64 * SEQ;

  for (int pass = 0; pass < 2; ++pass) {
    const int tile = pass ? gw : (31 - gw);
    const int qrow0 = tile * 32;
    const int q = qrow0 + c;
    const unsigned short* qbase = Qb + (((size_t)(n * NH + h)) * SEQ + qrow0) * 64;

    bf16x8 qf[4];
#pragma unroll
    for (int cc = 0; cc < 4; ++cc)
      qf[cc] = *(const bf16x8*)&qbase[c * 64 + cc * 16 + hi * 8];

    f32x16 o0 = {}, o1 = {};
    float m_run = -1e30f, l_run = 0.f;

    for (int kt = 0; kt < qrow0 + 32; kt += 64) {
      f32x16 s0 = {}, s1 = {};
#pragma unroll
      for (int cc = 0; cc < 4; ++cc) {
        bf16x8 k0 = *(const bf16x8*)&kbase[(size_t)(kt + c) * 64 + cc * 16 + hi * 8];
        bf16x8 k1 = *(const bf16x8*)&kbase[(size_t)(kt + 32 + c) * 64 + cc * 16 + hi * 8];
        s0 = __builtin_amdgcn_mfma_f32_32x32x16_bf16(k0, qf[cc], s0, 0, 0, 0);
        s1 = __builtin_amdgcn_mfma_f32_32x32x16_bf16(k1, qf[cc], s1, 0, 0, 0);
      }
      if (kt + 63 > qrow0) {
#pragma unroll
        for (int r = 0; r < 16; ++r) {
          const int key0 = kt + (r & 3) + 8 * (r >> 2) + 4 * hi;
          s0[r] = (key0 > q) ? -1e30f : s0[r];
          s1[r] = (key0 + 32 > q) ? -1e30f : s1[r];
        }
      }
      float tt[16];
#pragma unroll
      for (int r = 0; r < 16; ++r) tt[r] = fmaxf(s0[r], s1[r]);
#pragma unroll
      for (int st = 8; st > 0; st >>= 1)
#pragma unroll
        for (int r = 0; r < 8; ++r) if (r < st) tt[r] = fmaxf(tt[r], tt[r + st]);
      float mx = fmaxf(tt[0], __shfl_xor(tt[0], 32));
      const float mnew = fmaxf(m_run, mx);
      const float aa = fast_exp2(m_run - mnew);
#pragma unroll
      for (int r = 0; r < 16; ++r) {
        s0[r] = fast_exp2(s0[r] - mnew);
        s1[r] = fast_exp2(s1[r] - mnew);
      }
      float ps = 0.f;
#pragma unroll
      for (int r = 0; r < 16; ++r) ps += s0[r] + s1[r];
      ps += __shfl_xor(ps, 32);
      l_run = l_run * aa + ps;
      m_run = mnew;
#pragma unroll
      for (int r = 0; r < 16; ++r) { o0[r] *= aa; o1[r] *= aa; }

#pragma unroll
      for (int half = 0; half < 2; ++half) {
#pragma unroll
        for (int ccl = 0; ccl < 2; ++ccl) {
          const int cg = half * 2 + ccl;
          unsigned a0, a1, b0, b1;
          if (half == 0) {
            a0 = cvtpk_bf16(s0[8 * ccl + 0], s0[8 * ccl + 1]);
            a1 = cvtpk_bf16(s0[8 * ccl + 2], s0[8 * ccl + 3]);
            b0 = cvtpk_bf16(s0[8 * ccl + 4], s0[8 * ccl + 5]);
            b1 = cvtpk_bf16(s0[8 * ccl + 6], s0[8 * ccl + 7]);
          } else {
            a0 = cvtpk_bf16(s1[8 * ccl + 0], s1[8 * ccl + 1]);
            a1 = cvtpk_bf16(s1[8 * ccl + 2], s1[8 * ccl + 3]);
            b0 = cvtpk_bf16(s1[8 * ccl + 4], s1[8 * ccl + 5]);
            b1 = cvtpk_bf16(s1[8 * ccl + 6], s1[8 * ccl + 7]);
          }
          unsigned xa0 = __shfl_xor(a0, 32), xa1 = __shfl_xor(a1, 32);
          unsigned xb0 = __shfl_xor(b0, 32), xb1 = __shfl_xor(b1, 32);
          u32x4 fw;
          fw[0] = hi ? xb0 : a0;
          fw[1] = hi ? xb1 : a1;
          fw[2] = hi ? b0 : xa0;
          fw[3] = hi ? b1 : xa1;
          union { u32x4 u; bf16x8 b; } pf; pf.u = fw;
          bf16x8 v0 = *(const bf16x8*)&vtbase[(size_t)c * SEQ + kt + cg * 16 + hi * 8];
          bf16x8 v1 = *(const bf16x8*)&vtbase[(size_t)(32 + c) * SEQ + kt + cg * 16 + hi * 8];
          o0 = __builtin_amdgcn_mfma_f32_32x32x16_bf16(v0, pf.b, o0, 0, 0, 0);
          o1 = __builtin_amdgcn_mfma_f32_32x32x16_bf16(v1, pf.b, o1, 0, 0, 0);
        }
      }
    }

    const float inv = 1.0f / l_run;
    const size_t rowoff = (size_t)(n * SEQ + q) * D_MODEL + h * 64;
#pragma unroll
    for (int rr = 0; rr < 4; ++rr) {
      ushort4 w0, w1;
      w0.x = f2bf(o0[4 * rr + 0] * inv); w0.y = f2bf(o0[4 * rr + 1] * inv);
      w0.z = f2bf(o0[4 * rr + 2] * inv); w0.w = f2bf(o0[4 * rr + 3] * inv);
      w1.x = f2bf(o1[4 * rr + 0] * inv); w1.y = f2bf(o1[4 * rr + 1] * inv);
      w1.z = f2bf(o1[4 * rr + 2] * inv); w1.w = f2bf(o1[4 * rr + 3] * inv);
      *(ushort4*)&attnb[rowoff + 8 * rr + 4 * hi] = w0;
      *(ushort4*)&attnb[rowoff + 32 + 8 * rr + 4 * hi] = w1;
    }
  }
}

extern "C" void kernel_launch(void* const* d_in, const int* in_sizes, int n_in,
                              void* d_out, int out_size, void* d_ws, size_t ws_size,
                              hipStream_t stream) {
  const float* hs = (const float*)d_in[0];
  const float* wqkv = (const float*)d_in[1];
  const float* wdense = (const float*)d_in[2];
  float* out = (float*)d_out;
  char* ws = (char*)d_ws;

  unsigned short* hsb   = (unsigned short*)(ws + 0);            // 18,612,224
  unsigned short* wqkvb = (unsigned short*)(ws + 18612224);     // 44,208,128
  unsigned short* wdb   = (unsigned short*)(ws + 62820352);     // 41,881,600
  float*          fused = (float*)(ws + 104701952);             // 38,797,312
  unsigned short* qb    = (unsigned short*)(ws + 143499264);    // 18,612,224
  unsigned short* kb    = (unsigned short*)(ws + 162111488);    // 262,144
  unsigned short* vtb   = (unsigned short*)(ws + 162373632);    // 262,144
  unsigned short* attnb = (unsigned short*)(ws + 162635776);    // 18,612,224
  // total: 181,248,000

  {
    int total = M_ROWS * (D_MODEL / 4);
    convert_pad<<<(total + 255) / 256, 256, 0, stream>>>(hs, hsb, M_ROWS, M_ROWS, D_MODEL);
  }
  {
    int total = E_PAD2 * (D_MODEL / 4);
    convert_pad<<<(total + 255) / 256, 256, 0, stream>>>(wqkv, wqkvb, E_QKV, E_PAD2, D_MODEL);
  }
  {
    int total = D_PAD * (D_MODEL / 4);
    convert_pad<<<(total + 255) / 256, 256, 0, stream>>>(wdense, wdb, D_MODEL, D_PAD, D_MODEL);
  }
  gemm256<<<dim3(8 * 19), 512, 0, stream>>>(hsb, wqkvb, fused, D_MODEL, 19, E_STR, E_STR);
  {
    int total = NB * SEQ * 73 * 64;
    rope_extract<<<(total + 255) / 256, 256, 0, stream>>>(fused, qb, kb, vtb);
  }
  attn_kernel<<<dim3(8, NH, NB), 128, 0, stream>>>(qb, kb, vtb, attnb);
  gemm256<<<dim3(8 * 18), 512, 0, stream>>>(attnb, wdb, out, D_MODEL, 18, D_MODEL, D_MODEL);
}

// Round 10
// 433.133 us; speedup vs baseline: 1.0589x; 1.0589x over previous
//
#include <hip/hip_runtime.h>

#define D_MODEL 4544
#define E_QKV   4672     // D + 2*64
#define E_STR   4736     // fused row stride (37*128)
#define E_PAD2  4864     // QKV weight rows padded (19*256)
#define D_PAD   4608     // dense weight rows padded (18*256)
#define NH      71
#define SEQ     1024
#define NB      2
#define M_ROWS  2048     // NB*SEQ

typedef __bf16 bf16_t;
typedef bf16_t bf16x8 __attribute__((ext_vector_type(8)));
typedef float f32x4 __attribute__((ext_vector_type(4)));
typedef float f32x16 __attribute__((ext_vector_type(16)));
typedef unsigned u32x4 __attribute__((ext_vector_type(4)));

typedef __attribute__((address_space(1))) const void* gas_ptr;
typedef __attribute__((address_space(3))) void* las_ptr;

static __device__ __forceinline__ unsigned short f2bf(float f) {
  union { float f; unsigned u; } v; v.f = f;
  unsigned r = (v.u + 0x7fffu + ((v.u >> 16) & 1u)) >> 16;
  return (unsigned short)r;
}

static __device__ __forceinline__ unsigned cvtpk_bf16(float lo, float hi) {
  unsigned r;
  asm("v_cvt_pk_bf16_f32 %0, %1, %2" : "=v"(r) : "v"(lo), "v"(hi));
  return r;
}

static __device__ __forceinline__ float fast_exp2(float x) {
  float r;
  asm("v_exp_f32 %0, %1" : "=v"(r) : "v"(x));
  return r;
}

// dst[rows_pad][cols] bf16 <- src[rows_src][cols] f32, pad rows zeroed.
__global__ void convert_pad(const float* __restrict__ src, unsigned short* __restrict__ dst,
                            int rows_src, int rows_pad, int cols) {
  int idx = blockIdx.x * 256 + threadIdx.x;
  int cols4 = cols >> 2;
  int total = rows_pad * cols4;
  if (idx >= total) return;
  int row = idx / cols4;
  int c4 = (idx - row * cols4) << 2;
  ushort4 o;
  if (row < rows_src) {
    const float4 v = *(const float4*)(src + (size_t)row * cols + c4);
    o.x = f2bf(v.x); o.y = f2bf(v.y); o.z = f2bf(v.z); o.w = f2bf(v.w);
  } else {
    o.x = 0; o.y = 0; o.z = 0; o.w = 0;
  }
  *(ushort4*)(dst + (size_t)row * cols + c4) = o;
}

// ---------------- 256x256 8-phase GEMM, split-K=3 (round-5 proven schedule,
// + round-7 pointer-precompute STAGE). LDS fragment-ordered, conflict-free.
#define REGION(b_, op_, kh_) (((((b_)*2+(op_))*2)+(kh_)) << 13)

#define STAGE(b_, op_, kh_, kt_) do {                                          \
  const unsigned short* _p0 = (op_) ? pB0 : pA0;                               \
  const unsigned short* _p1 = (op_) ? pB1 : pA1;                               \
  const int _koff = ((kt_) << 6) + ((kh_) << 5);                               \
  __builtin_amdgcn_global_load_lds((gas_ptr)(_p0 + _koff),                     \
      (las_ptr)(lds + REGION(b_, op_, kh_) + (wave << 9)), 16, 0, 0);          \
  __builtin_amdgcn_global_load_lds((gas_ptr)(_p1 + _koff),                     \
      (las_ptr)(lds + REGION(b_, op_, kh_) + ((8 + wave) << 9)), 16, 0, 0);    \
} while (0)

#define LDA4(b_, kh_, mh_) do {                                                \
  const unsigned short* _ab = lds + REGION(b_, 0, kh_);                        \
  _Pragma("unroll")                                                            \
  for (int _mm = 0; _mm < 4; ++_mm)                                            \
    a[_mm] = *(const bf16x8*)&_ab[((wm * 8 + (mh_) * 4 + _mm) << 9) + lane * 8]; \
} while (0)

#define LDB4(b_, kh_) do {                                                     \
  const unsigned short* _bp = lds + REGION(b_, 1, kh_);                        \
  _Pragma("unroll")                                                            \
  for (int _n = 0; _n < 4; ++_n)                                               \
    bv[_n] = *(const bf16x8*)&_bp[((wn * 4 + _n) << 9) + lane * 8];            \
} while (0)

#define MFMA16(mh_) do {                                                       \
  _Pragma("unroll")                                                            \
  for (int _mm = 0; _mm < 4; ++_mm)                                            \
    _Pragma("unroll")                                                          \
    for (int _n = 0; _n < 4; ++_n)                                             \
      acc[(mh_) * 4 + _mm][_n] = __builtin_amdgcn_mfma_f32_16x16x32_bf16(      \
          a[_mm], bv[_n], acc[(mh_) * 4 + _mm][_n], 0, 0, 0);                  \
} while (0)

__global__ __launch_bounds__(512, 2) void gemm256(
    const unsigned short* __restrict__ A,
    const unsigned short* __restrict__ B,
    float* __restrict__ C0, float* __restrict__ C1, float* __restrict__ C2,
    int K, int Ntiles, int ldc, int Nact, int chunk) {
  __shared__ __align__(16) unsigned short lds[65536];   // 128 KiB
  const int tid = threadIdx.x;
  const int wave = tid >> 6, lane = tid & 63;
  const int g = lane >> 4, c = lane & 15;
  const int wm = wave >> 2, wn = wave & 3;
  const int nwg = gridDim.x;
  const int swz = (blockIdx.x & 7) * (nwg >> 3) + (blockIdx.x >> 3);
  const int tilesTot = 8 * Ntiles;
  const int kc = swz / tilesTot;
  const int tile = swz - kc * tilesTot;
  const int bm = tile / Ntiles, bn = tile - bm * Ntiles;
  const size_t bRow = (size_t)bm * 256, bCol = (size_t)bn * 256;
  const int NTtot = K >> 6;
  const int kb = kc * chunk;
  const int nt = (NTtot - kb < chunk) ? (NTtot - kb) : chunk;
  float* __restrict__ C = (kc == 0) ? C0 : ((kc == 1) ? C1 : C2);

  const unsigned short* pA0 = A + (bRow + (size_t)(wave * 16 + c)) * K + g * 8;
  const unsigned short* pA1 = A + (bRow + (size_t)((8 + wave) * 16 + c)) * K + g * 8;
  const unsigned short* pB0 = B + (bCol + (size_t)(wave * 16 + c)) * K + g * 8;
  const unsigned short* pB1 = B + (bCol + (size_t)((8 + wave) * 16 + c)) * K + g * 8;

  f32x4 acc[8][4] = {};

  STAGE(0, 0, 0, kb); STAGE(0, 1, 0, kb); STAGE(0, 0, 1, kb); STAGE(0, 1, 1, kb);
  STAGE(1, 1, 0, kb + 1); STAGE(1, 0, 0, kb + 1); STAGE(1, 1, 1, kb + 1);
  asm volatile("s_waitcnt vmcnt(6)" ::: "memory");
  __builtin_amdgcn_s_barrier();

  for (int t = 0; t < nt; ++t) {
    const int b = t & 1;
    const int tn1 = kb + ((t + 1 < nt) ? t + 1 : 0);
    const int tn2 = kb + ((t + 2 < nt) ? t + 2 : 0);
    bf16x8 a[4], bv[4];
    LDA4(b, 0, 0); LDB4(b, 0);
    STAGE(b ^ 1, 0, 1, tn1);
    __builtin_amdgcn_s_barrier();
    asm volatile("s_waitcnt lgkmcnt(0)" ::: "memory");
    __builtin_amdgcn_s_setprio(1);
    MFMA16(0);
    __builtin_amdgcn_s_setprio(0);
    __builtin_amdgcn_s_barrier();
    LDA4(b, 0, 1);
    STAGE(b, 1, 0, tn2);
    __builtin_amdgcn_s_barrier();
    asm volatile("s_waitcnt lgkmcnt(0)" ::: "memory");
    __builtin_amdgcn_s_setprio(1);
    MFMA16(1);
    __builtin_amdgcn_s_setprio(0);
    __builtin_amdgcn_s_barrier();
    LDA4(b, 1, 0); LDB4(b, 1);
    STAGE(b, 0, 0, tn2);
    __builtin_amdgcn_s_barrier();
    asm volatile("s_waitcnt lgkmcnt(0)" ::: "memory");
    __builtin_amdgcn_s_setprio(1);
    MFMA16(0);
    __builtin_amdgcn_s_setprio(0);
    __builtin_amdgcn_s_barrier();
    LDA4(b, 1, 1);
    STAGE(b, 1, 1, tn2);
    __builtin_amdgcn_s_barrier();
    asm volatile("s_waitcnt lgkmcnt(0)" ::: "memory");
    __builtin_amdgcn_s_setprio(1);
    MFMA16(1);
    __builtin_amdgcn_s_setprio(0);
    asm volatile("s_waitcnt vmcnt(6)" ::: "memory");
    __builtin_amdgcn_s_barrier();
  }
  asm volatile("s_waitcnt vmcnt(0)" ::: "memory");

#pragma unroll
  for (int mm = 0; mm < 8; ++mm) {
#pragma unroll
    for (int n = 0; n < 4; ++n) {
      int col = (int)bCol + wn * 64 + n * 16 + c;
      if (col < Nact) {
#pragma unroll
        for (int r = 0; r < 4; ++r) {
          size_t row = bRow + wm * 128 + mm * 16 + g * 4 + r;
          C[row * ldc + col] = acc[mm][n][r];
        }
      }
    }
  }
}

// out = p0 + p1 + p2 (f32), float4-vectorized
__global__ void reduce3(const float* __restrict__ p0, const float* __restrict__ p1,
                        const float* __restrict__ p2, float* __restrict__ out, int total4) {
  int idx = blockIdx.x * 256 + threadIdx.x;
  if (idx >= total4) return;
  float4 a = *(const float4*)(p0 + (size_t)idx * 4);
  float4 b = *(const float4*)(p1 + (size_t)idx * 4);
  float4 cc = *(const float4*)(p2 + (size_t)idx * 4);
  float4 o;
  o.x = a.x + b.x + cc.x; o.y = a.y + b.y + cc.y;
  o.z = a.z + b.z + cc.z; o.w = a.w + b.w + cc.w;
  *(float4*)(out + (size_t)idx * 4) = o;
}

// fused partial-sum (np buffers) -> Qb (RoPE, *0.125*log2e), Kb (RoPE), VTb (V^T)
__global__ void rope_extract(const float* __restrict__ p0, const float* __restrict__ p1,
                             const float* __restrict__ p2, int np,
                             unsigned short* __restrict__ Qb,
                             unsigned short* __restrict__ Kb,
                             unsigned short* __restrict__ VTb) {
  int idx = blockIdx.x * 256 + threadIdx.x;
  const int total = NB * SEQ * 73 * 64;
  if (idx >= total) return;
  int d = idx & 63;
  int t = idx >> 6;
  int h = t % 73;  t /= 73;
  int l = t & (SEQ - 1);
  int n = t >> 10;
  const size_t base = ((size_t)(n * SEQ + l)) * E_STR + h * 64;
  float x = p0[base + d];
  if (np == 3) x += p1[base + d] + p2[base + d];
  if (h == 72) {
    VTb[((size_t)(n * 64 + d)) * SEQ + l] = f2bf(x);
    return;
  }
  int dh = d & 31;
  float inv = __expf(-(float)dh * (9.210340371976184f / 32.0f));
  float ang = (float)l * inv;
  float sn, cs;
  __sincosf(ang, &sn, &cs);
  int dx = (d < 32) ? d + 32 : d - 32;
  float xr = p0[base + dx];
  if (np == 3) xr += p1[base + dx] + p2[base + dx];
  float rh = (d < 32) ? -xr : xr;
  float out = x * cs + rh * sn;
  if (h == 71) {
    Kb[((size_t)(n * SEQ + l)) * 64 + d] = f2bf(out);
  } else {
    Qb[(((size_t)(n * NH + h)) * SEQ + l) * 64 + d] = f2bf(out * 0.1803368801111204f);
  }
}

// Swapped-QK^T flash MQA, per-wave causal pairing + K-prefetch + V-early-issue.
#define LOADK(dst_, ktv_) do {                                                 \
  _Pragma("unroll")                                                            \
  for (int _cc = 0; _cc < 4; ++_cc) {                                          \
    dst_[_cc]     = *(const bf16x8*)&kbase[(size_t)((ktv_) + c) * 64 + _cc * 16 + hi * 8];      \
    dst_[4 + _cc] = *(const bf16x8*)&kbase[(size_t)((ktv_) + 32 + c) * 64 + _cc * 16 + hi * 8]; \
  }                                                                            \
} while (0)

__global__ __launch_bounds__(128) void attn_kernel(
    const unsigned short* __restrict__ Qb,
    const unsigned short* __restrict__ Kb,
    const unsigned short* __restrict__ VTb,
    unsigned short* __restrict__ attnb) {
  const int h = blockIdx.y, n = blockIdx.z;
  const int wave = threadIdx.x >> 6, lane = threadIdx.x & 63;
  const int c = lane & 31, hi = lane >> 5;
  const int gw = blockIdx.x * 2 + wave;   // 0..15

  const unsigned short* kbase = Kb + (size_t)n * SEQ * 64;
  const unsigned short* vtbase = VTb + (size_t)n * 64 * SEQ;

  for (int pass = 0; pass < 2; ++pass) {
    const int tile = pass ? gw : (31 - gw);
    const int qrow0 = tile * 32;
    const int q = qrow0 + c;
    const int nk = qrow0 + 32;
    const unsigned short* qbase = Qb + (((size_t)(n * NH + h)) * SEQ + qrow0) * 64;

    bf16x8 qf[4];
#pragma unroll
    for (int cc = 0; cc < 4; ++cc)
      qf[cc] = *(const bf16x8*)&qbase[c * 64 + cc * 16 + hi * 8];

    f32x16 o0 = {}, o1 = {};
    float m_run = -1e30f, l_run = 0.f;

    bf16x8 kc[8], kn[8];
    LOADK(kc, 0);

    for (int kt = 0; kt < nk; kt += 64) {
      const bool more = (kt + 64) < nk;
      // ---- QK^T (swapped) on current K regs ----
      f32x16 s0 = {}, s1 = {};
#pragma unroll
      for (int cc = 0; cc < 4; ++cc) {
        s0 = __builtin_amdgcn_mfma_f32_32x32x16_bf16(kc[cc], qf[cc], s0, 0, 0, 0);
        s1 = __builtin_amdgcn_mfma_f32_32x32x16_bf16(kc[4 + cc], qf[cc], s1, 0, 0, 0);
      }
      // ---- prefetch next K tile; early-issue this tile's V ----
      if (more) LOADK(kn, kt + 64);
      bf16x8 vv0[4], vv1[4];
#pragma unroll
      for (int cg = 0; cg < 4; ++cg) {
        vv0[cg] = *(const bf16x8*)&vtbase[(size_t)c * SEQ + kt + cg * 16 + hi * 8];
        vv1[cg] = *(const bf16x8*)&vtbase[(size_t)(32 + c) * SEQ + kt + cg * 16 + hi * 8];
      }
      __builtin_amdgcn_sched_barrier(0);
      // ---- mask + online softmax (hides K/V latency) ----
      if (kt + 63 > qrow0) {
#pragma unroll
        for (int r = 0; r < 16; ++r) {
          const int key0 = kt + (r & 3) + 8 * (r >> 2) + 4 * hi;
          s0[r] = (key0 > q) ? -1e30f : s0[r];
          s1[r] = (key0 + 32 > q) ? -1e30f : s1[r];
        }
      }
      float tt[16];
#pragma unroll
      for (int r = 0; r < 16; ++r) tt[r] = fmaxf(s0[r], s1[r]);
#pragma unroll
      for (int st = 8; st > 0; st >>= 1)
#pragma unroll
        for (int r = 0; r < 8; ++r) if (r < st) tt[r] = fmaxf(tt[r], tt[r + st]);
      float mx = fmaxf(tt[0], __shfl_xor(tt[0], 32));
      const float mnew = fmaxf(m_run, mx);
      const float aa = fast_exp2(m_run - mnew);
#pragma unroll
      for (int r = 0; r < 16; ++r) {
        s0[r] = fast_exp2(s0[r] - mnew);
        s1[r] = fast_exp2(s1[r] - mnew);
      }
      float ps = 0.f;
#pragma unroll
      for (int r = 0; r < 16; ++r) ps += s0[r] + s1[r];
      ps += __shfl_xor(ps, 32);
      l_run = l_run * aa + ps;
      m_run = mnew;
#pragma unroll
      for (int r = 0; r < 16; ++r) { o0[r] *= aa; o1[r] *= aa; }

      // ---- P -> bf16 fragments; PV on early-issued V regs ----
#pragma unroll
      for (int half = 0; half < 2; ++half) {
#pragma unroll
        for (int ccl = 0; ccl < 2; ++ccl) {
          const int cg = half * 2 + ccl;
          unsigned a0, a1, b0, b1;
          if (half == 0) {
            a0 = cvtpk_bf16(s0[8 * ccl + 0], s0[8 * ccl + 1]);
            a1 = cvtpk_bf16(s0[8 * ccl + 2], s0[8 * ccl + 3]);
            b0 = cvtpk_bf16(s0[8 * ccl + 4], s0[8 * ccl + 5]);
            b1 = cvtpk_bf16(s0[8 * ccl + 6], s0[8 * ccl + 7]);
          } else {
            a0 = cvtpk_bf16(s1[8 * ccl + 0], s1[8 * ccl + 1]);
            a1 = cvtpk_bf16(s1[8 * ccl + 2], s1[8 * ccl + 3]);
            b0 = cvtpk_bf16(s1[8 * ccl + 4], s1[8 * ccl + 5]);
            b1 = cvtpk_bf16(s1[8 * ccl + 6], s1[8 * ccl + 7]);
          }
          unsigned xa0 = __shfl_xor(a0, 32), xa1 = __shfl_xor(a1, 32);
          unsigned xb0 = __shfl_xor(b0, 32), xb1 = __shfl_xor(b1, 32);
          u32x4 fw;
          fw[0] = hi ? xb0 : a0;
          fw[1] = hi ? xb1 : a1;
          fw[2] = hi ? b0 : xa0;
          fw[3] = hi ? b1 : xa1;
          union { u32x4 u; bf16x8 b; } pf; pf.u = fw;
          o0 = __builtin_amdgcn_mfma_f32_32x32x16_bf16(vv0[cg], pf.b, o0, 0, 0, 0);
          o1 = __builtin_amdgcn_mfma_f32_32x32x16_bf16(vv1[cg], pf.b, o1, 0, 0, 0);
        }
      }
      // ---- rotate prefetched K into place ----
      if (more) {
#pragma unroll
        for (int cc = 0; cc < 8; ++cc) kc[cc] = kn[cc];
      }
    }

    const float inv = 1.0f / l_run;
    const size_t rowoff = (size_t)(n * SEQ + q) * D_MODEL + h * 64;
#pragma unroll
    for (int rr = 0; rr < 4; ++rr) {
      ushort4 w0, w1;
      w0.x = f2bf(o0[4 * rr + 0] * inv); w0.y = f2bf(o0[4 * rr + 1] * inv);
      w0.z = f2bf(o0[4 * rr + 2] * inv); w0.w = f2bf(o0[4 * rr + 3] * inv);
      w1.x = f2bf(o1[4 * rr + 0] * inv); w1.y = f2bf(o1[4 * rr + 1] * inv);
      w1.z = f2bf(o1[4 * rr + 2] * inv); w1.w = f2bf(o1[4 * rr + 3] * inv);
      *(ushort4*)&attnb[rowoff + 8 * rr + 4 * hi] = w0;
      *(ushort4*)&attnb[rowoff + 32 + 8 * rr + 4 * hi] = w1;
    }
  }
}

extern "C" void kernel_launch(void* const* d_in, const int* in_sizes, int n_in,
                              void* d_out, int out_size, void* d_ws, size_t ws_size,
                              hipStream_t stream) {
  const float* hs = (const float*)d_in[0];
  const float* wqkv = (const float*)d_in[1];
  const float* wdense = (const float*)d_in[2];
  float* out = (float*)d_out;
  char* ws = (char*)d_ws;

  unsigned short* hsb   = (unsigned short*)(ws + 0);            // 18,612,224
  unsigned short* wqkvb = (unsigned short*)(ws + 18612224);     // 44,208,128
  unsigned short* wdb   = (unsigned short*)(ws + 62820352);     // 41,881,600
  float*          fused = (float*)(ws + 104701952);             // 38,797,312
  unsigned short* qb    = (unsigned short*)(ws + 143499264);    // 18,612,224
  unsigned short* kb    = (unsigned short*)(ws + 162111488);    // 262,144
  unsigned short* vtb   = (unsigned short*)(ws + 162373632);    // 262,144
  unsigned short* attnb = (unsigned short*)(ws + 162635776);    // 18,612,224
  // base end: 181,248,000
  float* fusedE1 = (float*)(ws + 181248000);                    // 38,797,312
  float* fusedE2 = (float*)(ws + 220045312);                    // 38,797,312
  const int splitOK = (ws_size >= (size_t)258842624) ? 1 : 0;

  {
    int total = M_ROWS * (D_MODEL / 4);
    convert_pad<<<(total + 255) / 256, 256, 0, stream>>>(hs, hsb, M_ROWS, M_ROWS, D_MODEL);
  }
  {
    int total = E_PAD2 * (D_MODEL / 4);
    convert_pad<<<(total + 255) / 256, 256, 0, stream>>>(wqkv, wqkvb, E_QKV, E_PAD2, D_MODEL);
  }
  {
    int total = D_PAD * (D_MODEL / 4);
    convert_pad<<<(total + 255) / 256, 256, 0, stream>>>(wdense, wdb, D_MODEL, D_PAD, D_MODEL);
  }

  if (splitOK) {
    gemm256<<<dim3(8 * 19 * 3), 512, 0, stream>>>(hsb, wqkvb, fused, fusedE1, fusedE2,
                                                  D_MODEL, 19, E_STR, E_STR, 24);
  } else {
    gemm256<<<dim3(8 * 19), 512, 0, stream>>>(hsb, wqkvb, fused, fused, fused,
                                              D_MODEL, 19, E_STR, E_STR, 71);
  }
  {
    int total = NB * SEQ * 73 * 64;
    rope_extract<<<(total + 255) / 256, 256, 0, stream>>>(fused, fusedE1, fusedE2,
                                                          splitOK ? 3 : 1, qb, kb, vtb);
  }
  attn_kernel<<<dim3(8, NH, NB), 128, 0, stream>>>(qb, kb, vtb, attnb);
  if (splitOK) {
    float* p0 = (float*)(ws + 0);
    float* p1 = fused;
    float* p2 = fusedE1;
    gemm256<<<dim3(8 * 18 * 3), 512, 0, stream>>>(attnb, wdb, p0, p1, p2,
                                                  D_MODEL, 18, D_MODEL, D_MODEL, 24);
    int total4 = (M_ROWS * D_MODEL) / 4;
    reduce3<<<(total4 + 255) / 256, 256, 0, stream>>>(p0, p1, p2, out, total4);
  } else {
    gemm256<<<dim3(8 * 18), 512, 0, stream>>>(attnb, wdb, out, out, out,
                                              D_MODEL, 18, D_MODEL, D_MODEL, 71);
  }
}